// Round 2
// baseline (487.506 us; speedup 1.0000x reference)
//
#include <hip/hip_runtime.h>
#include <hip/hip_bf16.h>

#define BDIM 8
#define NTOK 8192
#define CDIM 256
#define HEADS 4
#define DHEAD 64
#define MROWS (BDIM * NTOK)   // 65536

typedef unsigned short ushort_t;
typedef short bf16x8 __attribute__((ext_vector_type(8)));
typedef float f32x4 __attribute__((ext_vector_type(4)));
typedef unsigned short u16x8 __attribute__((ext_vector_type(8)));
typedef unsigned short u16x4 __attribute__((ext_vector_type(4)));

__device__ inline ushort_t f2bf(float f) {
    __hip_bfloat16 h = __float2bfloat16(f);
    return *reinterpret_cast<ushort_t*>(&h);
}

__device__ inline u16x8 pack8(float4 a, float4 b) {
    u16x8 o;
    o[0] = f2bf(a.x); o[1] = f2bf(a.y); o[2] = f2bf(a.z); o[3] = f2bf(a.w);
    o[4] = f2bf(b.x); o[5] = f2bf(b.y); o[6] = f2bf(b.z); o[7] = f2bf(b.w);
    return o;
}

// ---------------------------------------------------------------------------
__global__ __launch_bounds__(256) void zero_kernel(float* __restrict__ p, int n) {
    int i = blockIdx.x * 256 + threadIdx.x;
    if (i < n) p[i] = 0.0f;
}

// ---------------------------------------------------------------------------
// Pipelined MFMA projection: out[m][c] = sum_k A[m][k]*W[c][k], fp32 in, bf16 out.
// 128x128 tile, BK=32 (8 iters). 2-DEEP VGPR prefetch (256 B/thread in flight ->
// counted vmcnt instead of drain), in-reg fp32->bf16 cvt, double-buffered LDS,
// ONE raw s_barrier per iter. Fused per-column sum-of-squares.
__global__ __launch_bounds__(256, 4) void proj_mfma(
    const float* __restrict__ x1, const float* __restrict__ x2,
    const float* __restrict__ Wq, const float* __restrict__ Wk,
    const float* __restrict__ Wv,
    ushort_t* __restrict__ qp, ushort_t* __restrict__ kp, ushort_t* __restrict__ vp,
    float* __restrict__ ssq, float* __restrict__ ssk)
{
    const float* A; const float* W; ushort_t* outp; float* ss;
    if (blockIdx.z == 0)      { A = x1; W = Wq; outp = qp; ss = ssq; }
    else if (blockIdx.z == 1) { A = x2; W = Wk; outp = kp; ss = ssk; }
    else                      { A = x2; W = Wv; outp = vp; ss = nullptr; }

    // LDS 16B-slot layout per buffer: slot = kg*128 + row (kg = k/8 within BK=32)
    __shared__ ushort_t Asl[2][4096];   // 2 x 8 KB
    __shared__ ushort_t Bsl[2][4096];
    __shared__ float colss[128];

    const int t = threadIdx.x;
    const int lane = t & 63, w = t >> 6;
    const int l16 = lane & 15, quad = lane >> 4;
    const int m0 = blockIdx.x * 128, c0 = blockIdx.y * 128;
    const int wm = (w >> 1) * 64, wn = (w & 1) * 64;

    const int srow = t >> 1;   // 0..127
    const int skh  = t & 1;    // k-half: floats [skh*16, skh*16+16)

    const float* Ap = A + (size_t)(m0 + srow) * CDIM + skh * 16;
    const float* Wp = W + (size_t)(c0 + srow) * CDIM + skh * 16;

    // 2-deep prefetch: stage s holds the k-chunk next consumed when it&1==s
    float4 ga[2][4], gb[2][4];
#pragma unroll
    for (int s = 0; s < 2; ++s)
#pragma unroll
        for (int i = 0; i < 4; ++i) {
            ga[s][i] = *(const float4*)(Ap + s * 32 + i * 4);
            gb[s][i] = *(const float4*)(Wp + s * 32 + i * 4);
        }

    f32x4 acc[4][4] = {};

#pragma unroll
    for (int it = 0; it < 8; ++it) {
        const int p = it & 1;
        ushort_t* As = Asl[p];
        ushort_t* Bs = Bsl[p];
        *(u16x8*)&As[(skh * 2 + 0) * 1024 + srow * 8] = pack8(ga[p][0], ga[p][1]);
        *(u16x8*)&As[(skh * 2 + 1) * 1024 + srow * 8] = pack8(ga[p][2], ga[p][3]);
        *(u16x8*)&Bs[(skh * 2 + 0) * 1024 + srow * 8] = pack8(gb[p][0], gb[p][1]);
        *(u16x8*)&Bs[(skh * 2 + 1) * 1024 + srow * 8] = pack8(gb[p][2], gb[p][3]);
        if (it < 6) {
            const int ko = (it + 2) * 32;
#pragma unroll
            for (int i = 0; i < 4; ++i) {
                ga[p][i] = *(const float4*)(Ap + ko + i * 4);
                gb[p][i] = *(const float4*)(Wp + ko + i * 4);
            }
        }
        asm volatile("s_waitcnt lgkmcnt(0)" ::: "memory");
        __builtin_amdgcn_s_barrier();
        bf16x8 aF[4], bF[4];
#pragma unroll
        for (int i = 0; i < 4; ++i)
            aF[i] = *(const bf16x8*)&As[quad * 1024 + (wm + i * 16 + l16) * 8];
#pragma unroll
        for (int j = 0; j < 4; ++j)
            bF[j] = *(const bf16x8*)&Bs[quad * 1024 + (wn + j * 16 + l16) * 8];
#pragma unroll
        for (int i = 0; i < 4; ++i)
#pragma unroll
            for (int j = 0; j < 4; ++j)
                acc[i][j] = __builtin_amdgcn_mfma_f32_16x16x32_bf16(aF[i], bF[j], acc[i][j], 0, 0, 0);
    }

    // epilogue: C/D layout col=lane&15, row=quad*4+reg
#pragma unroll
    for (int i = 0; i < 4; ++i) {
#pragma unroll
        for (int j = 0; j < 4; ++j) {
            int col = c0 + wn + j * 16 + l16;
#pragma unroll
            for (int reg = 0; reg < 4; ++reg) {
                int row = m0 + wm + i * 16 + quad * 4 + reg;
                outp[(size_t)row * CDIM + col] = f2bf(acc[i][j][reg]);
            }
        }
    }

    if (ss) {
        __syncthreads();
        if (t < 128) colss[t] = 0.0f;
        __syncthreads();
#pragma unroll
        for (int j = 0; j < 4; ++j) {
            float s = 0.0f;
#pragma unroll
            for (int i = 0; i < 4; ++i)
#pragma unroll
                for (int reg = 0; reg < 4; ++reg)
                    s += acc[i][j][reg] * acc[i][j][reg];
            atomicAdd(&colss[wn + j * 16 + l16], s);
        }
        __syncthreads();
        if (t < 128) {
            int b = m0 >> 13;   // 128-row tile never crosses a batch
            atomicAdd(&ss[b * CDIM + c0 + t], colss[t]);
        }
    }
}

// ---------------------------------------------------------------------------
// MFMA Gram: G[b][h][d][e] += sum_n qp[b][n][h*64+d] * kp[b][n][h*64+e]
// grid (16 slabs, H, B). Stage [64 c][128 n] transposed in LDS (stride 144).
// 1-deep chunk prefetch: loads for chunk c+1 issued right after the LDS
// transpose-writes of chunk c, hidden under the MFMA phase.
__global__ __launch_bounds__(256) void gram_mfma(
    const ushort_t* __restrict__ qp, const ushort_t* __restrict__ kp,
    float* __restrict__ G)
{
    constexpr int NS = 144;  // padded n-stride (16B-aligned, b128-conflict-free)
    __shared__ ushort_t qs[64 * NS];   // 18 KB
    __shared__ ushort_t ks2[64 * NS];  // 18 KB
    __shared__ float gsum[4096];       // 16 KB

    const int t = threadIdx.x;
    const int lane = t & 63, w = t >> 6;
    const int l16 = lane & 15, quad = lane >> 4;
    const int slab = blockIdx.x, h = blockIdx.y, b = blockIdx.z;
    const size_t base = (size_t)b * NTOK * CDIM + h * DHEAD;

    const int cg  = t >> 5;   // 0..7 -> channels cg*8..+7
    const int ng4 = t & 31;   // 0..31 -> tokens ng4*4..+3

    for (int i = t; i < 4096; i += 256) gsum[i] = 0.0f;

    f32x4 acc[4][4] = {};

    u16x8 qv[2][4], kv[2][4];
#pragma unroll
    for (int i = 0; i < 4; ++i) {
        size_t g = base + (size_t)(slab * 512 + ng4 * 4 + i) * CDIM + cg * 8;
        qv[0][i] = *(const u16x8*)&qp[g];
        kv[0][i] = *(const u16x8*)&kp[g];
    }

#pragma unroll
    for (int cch = 0; cch < 4; ++cch) {
        const int p = cch & 1;
        __syncthreads();   // previous chunk's LDS reads complete
#pragma unroll
        for (int j = 0; j < 8; ++j) {
            u16x4 wq, wk;
            wq[0] = qv[p][0][j]; wq[1] = qv[p][1][j]; wq[2] = qv[p][2][j]; wq[3] = qv[p][3][j];
            wk[0] = kv[p][0][j]; wk[1] = kv[p][1][j]; wk[2] = kv[p][2][j]; wk[3] = kv[p][3][j];
            *(u16x4*)&qs[(cg * 8 + j) * NS + ng4 * 4] = wq;
            *(u16x4*)&ks2[(cg * 8 + j) * NS + ng4 * 4] = wk;
        }
        if (cch < 3) {
#pragma unroll
            for (int i = 0; i < 4; ++i) {
                size_t g = base + (size_t)(slab * 512 + (cch + 1) * 128 + ng4 * 4 + i) * CDIM + cg * 8;
                qv[p ^ 1][i] = *(const u16x8*)&qp[g];
                kv[p ^ 1][i] = *(const u16x8*)&kp[g];
            }
        }
        __syncthreads();
        // wave w computes tokens [w*32, w*32+32): A[m=d][k=n], B[k=n][col=e]
        bf16x8 aF[4], bF[4];
#pragma unroll
        for (int i = 0; i < 4; ++i)
            aF[i] = *(const bf16x8*)&qs[(i * 16 + l16) * NS + w * 32 + quad * 8];
#pragma unroll
        for (int j = 0; j < 4; ++j)
            bF[j] = *(const bf16x8*)&ks2[(j * 16 + l16) * NS + w * 32 + quad * 8];
#pragma unroll
        for (int i = 0; i < 4; ++i)
#pragma unroll
            for (int j = 0; j < 4; ++j)
                acc[i][j] = __builtin_amdgcn_mfma_f32_16x16x32_bf16(aF[i], bF[j], acc[i][j], 0, 0, 0);
    }

    __syncthreads();
#pragma unroll
    for (int i = 0; i < 4; ++i)
#pragma unroll
        for (int j = 0; j < 4; ++j)
#pragma unroll
            for (int reg = 0; reg < 4; ++reg)
                atomicAdd(&gsum[(i * 16 + quad * 4 + reg) * 64 + j * 16 + l16], acc[i][j][reg]);
    __syncthreads();

    float* Gp = G + (size_t)(b * HEADS + h) * 4096;
    for (int i = t; i < 4096; i += 256) atomicAdd(&Gp[i], gsum[i]);
}

// ---------------------------------------------------------------------------
// K3 (fused): normalize + temperature + row softmax (in LDS, never written back)
// then W_eff[b][c][h*64+e] = sum_d Wo[c][h*64+d] * attn[d][e], bf16 out.
// Softmax: 4 lanes per row (16 cols each), shfl_xor combine within wave.
__global__ __launch_bounds__(256) void softmax_weff(
    const float* __restrict__ G, const float* __restrict__ ssq,
    const float* __restrict__ ssk, const float* __restrict__ temp,
    const float* __restrict__ Wo, ushort_t* __restrict__ Weffb)
{
    const int h = blockIdx.x, b = blockIdx.y;
    const int t = threadIdx.x;
    __shared__ float at[64][65];
    __shared__ float nk[64];

    if (t < 64) nk[t] = fmaxf(sqrtf(ssk[b * CDIM + h * DHEAD + t]), 1e-12f);
    __syncthreads();

    {
        const int row = t >> 2, part = t & 3;
        const float* Grow = G + (size_t)(b * HEADS + h) * 4096 + row * 64;
        const float tmp = temp[h];
        const float nq = fmaxf(sqrtf(ssq[b * CDIM + h * DHEAD + row]), 1e-12f);

        float vals[16];
        float mx = -1e30f;
#pragma unroll
        for (int j = 0; j < 16; ++j) {
            int e = part * 16 + j;
            float v = Grow[e] / (nq * nk[e]) * tmp;
            vals[j] = v;
            mx = fmaxf(mx, v);
        }
        mx = fmaxf(mx, __shfl_xor(mx, 1));
        mx = fmaxf(mx, __shfl_xor(mx, 2));
        float s = 0.0f;
#pragma unroll
        for (int j = 0; j < 16; ++j) {
            float ev = __expf(vals[j] - mx);
            vals[j] = ev;
            s += ev;
        }
        s += __shfl_xor(s, 1);
        s += __shfl_xor(s, 2);
        float inv = 1.0f / s;
#pragma unroll
        for (int j = 0; j < 16; ++j)
            at[row][part * 16 + j] = vals[j] * inv;
    }
    __syncthreads();

    const int c = t;
    float wo[64];
#pragma unroll
    for (int d2 = 0; d2 < 64; ++d2) wo[d2] = Wo[(size_t)c * CDIM + h * DHEAD + d2];

    ushort_t* Wb = Weffb + (size_t)b * CDIM * CDIM + (size_t)c * CDIM + h * DHEAD;
#pragma unroll 4
    for (int e = 0; e < 64; ++e) {
        float s = 0.0f;
#pragma unroll
        for (int d2 = 0; d2 < 64; ++d2) s += wo[d2] * at[d2][e];
        Wb[e] = f2bf(s);
    }
}

// ---------------------------------------------------------------------------
// Pipelined MFMA output GEMM: out[m][c] = bo[c] + sum_k vp[m][k]*Weffb[b][c][k]
// Same skeleton as proj_mfma with 2-deep VGPR prefetch, bf16 inputs (no cvt).
__global__ __launch_bounds__(256, 4) void out_mfma(
    const ushort_t* __restrict__ vp, const ushort_t* __restrict__ Weffb,
    const float* __restrict__ bo, float* __restrict__ out)
{
    __shared__ ushort_t Asl[2][4096];
    __shared__ ushort_t Bsl[2][4096];

    const int t = threadIdx.x;
    const int lane = t & 63, w = t >> 6;
    const int l16 = lane & 15, quad = lane >> 4;
    const int m0 = blockIdx.x * 128, c0 = blockIdx.y * 128;
    const int wm = (w >> 1) * 64, wn = (w & 1) * 64;

    const int srow = t >> 1;
    const int skh  = t & 1;

    const ushort_t* Ap = vp + (size_t)(m0 + srow) * CDIM + skh * 16;
    const ushort_t* Bp = Weffb + (size_t)(m0 >> 13) * CDIM * CDIM
                       + (size_t)(c0 + srow) * CDIM + skh * 16;

    u16x8 ga[2][2], gb[2][2];
#pragma unroll
    for (int s = 0; s < 2; ++s) {
        ga[s][0] = *(const u16x8*)(Ap + s * 32);
        ga[s][1] = *(const u16x8*)(Ap + s * 32 + 8);
        gb[s][0] = *(const u16x8*)(Bp + s * 32);
        gb[s][1] = *(const u16x8*)(Bp + s * 32 + 8);
    }

    f32x4 acc[4][4] = {};

#pragma unroll
    for (int it = 0; it < 8; ++it) {
        const int p = it & 1;
        ushort_t* As = Asl[p];
        ushort_t* Bs = Bsl[p];
        *(u16x8*)&As[(skh * 2 + 0) * 1024 + srow * 8] = ga[p][0];
        *(u16x8*)&As[(skh * 2 + 1) * 1024 + srow * 8] = ga[p][1];
        *(u16x8*)&Bs[(skh * 2 + 0) * 1024 + srow * 8] = gb[p][0];
        *(u16x8*)&Bs[(skh * 2 + 1) * 1024 + srow * 8] = gb[p][1];
        if (it < 6) {
            const int ko = (it + 2) * 32;
            ga[p][0] = *(const u16x8*)(Ap + ko);
            ga[p][1] = *(const u16x8*)(Ap + ko + 8);
            gb[p][0] = *(const u16x8*)(Bp + ko);
            gb[p][1] = *(const u16x8*)(Bp + ko + 8);
        }
        asm volatile("s_waitcnt lgkmcnt(0)" ::: "memory");
        __builtin_amdgcn_s_barrier();
        bf16x8 aF[4], bF[4];
#pragma unroll
        for (int i = 0; i < 4; ++i)
            aF[i] = *(const bf16x8*)&As[quad * 1024 + (wm + i * 16 + l16) * 8];
#pragma unroll
        for (int j = 0; j < 4; ++j)
            bF[j] = *(const bf16x8*)&Bs[quad * 1024 + (wn + j * 16 + l16) * 8];
#pragma unroll
        for (int i = 0; i < 4; ++i)
#pragma unroll
            for (int j = 0; j < 4; ++j)
                acc[i][j] = __builtin_amdgcn_mfma_f32_16x16x32_bf16(aF[i], bF[j], acc[i][j], 0, 0, 0);
    }

#pragma unroll
    for (int i = 0; i < 4; ++i) {
#pragma unroll
        for (int j = 0; j < 4; ++j) {
            int col = c0 + wn + j * 16 + l16;
            float bias = bo[col];
#pragma unroll
            for (int reg = 0; reg < 4; ++reg) {
                int row = m0 + wm + i * 16 + quad * 4 + reg;
                out[(size_t)row * CDIM + col] = acc[i][j][reg] + bias;
            }
        }
    }
}

// ---------------------------------------------------------------------------
extern "C" void kernel_launch(void* const* d_in, const int* in_sizes, int n_in,
                              void* d_out, int out_size, void* d_ws, size_t ws_size,
                              hipStream_t stream) {
    const float* x1   = (const float*)d_in[0];
    const float* x2   = (const float*)d_in[1];
    const float* Wq   = (const float*)d_in[2];
    const float* Wk   = (const float*)d_in[3];
    const float* Wv   = (const float*)d_in[4];
    const float* Wo   = (const float*)d_in[5];
    const float* bo   = (const float*)d_in[6];
    const float* temp = (const float*)d_in[7];
    float* out = (float*)d_out;

    char* ws = (char*)d_ws;
    const size_t SZP = (size_t)MROWS * CDIM * sizeof(ushort_t);   // 32 MB
    ushort_t* qp   = (ushort_t*)(ws);
    ushort_t* kp   = (ushort_t*)(ws + SZP);
    ushort_t* vp   = (ushort_t*)(ws + 2 * SZP);
    float*    ssq  = (float*)(ws + 3 * SZP);                 // 8 KB
    float*    ssk  = (float*)(ws + 3 * SZP + 8192);          // 8 KB
    float*    G    = (float*)(ws + 3 * SZP + 16384);         // 512 KB
    ushort_t* Weffb= (ushort_t*)(ws + 3 * SZP + 540672);     // 1 MB

    // zero ssq+ssk+G (contiguous, 135168 floats)
    zero_kernel<<<dim3((135168 + 255) / 256), dim3(256), 0, stream>>>(ssq, 135168);

    proj_mfma<<<dim3(MROWS / 128, CDIM / 128, 3), dim3(256), 0, stream>>>(
        x1, x2, Wq, Wk, Wv, qp, kp, vp, ssq, ssk);

    gram_mfma<<<dim3(16, HEADS, BDIM), dim3(256), 0, stream>>>(qp, kp, G);

    softmax_weff<<<dim3(HEADS, BDIM), dim3(256), 0, stream>>>(G, ssq, ssk, temp, Wo, Weffb);

    out_mfma<<<dim3(MROWS / 128, CDIM / 128), dim3(256), 0, stream>>>(vp, Weffb, bo, out);
}

// Round 3
// 351.598 us; speedup vs baseline: 1.3865x; 1.3865x over previous
//
#include <hip/hip_runtime.h>
#include <hip/hip_bf16.h>

#define BDIM 8
#define NTOK 8192
#define CDIM 256
#define HEADS 4
#define DHEAD 64
#define MROWS (BDIM * NTOK)   // 65536
#define NSLAB 16

typedef unsigned short ushort_t;
typedef short bf16x8 __attribute__((ext_vector_type(8)));
typedef float f32x4 __attribute__((ext_vector_type(4)));
typedef unsigned short u16x8 __attribute__((ext_vector_type(8)));
typedef unsigned short u16x4 __attribute__((ext_vector_type(4)));

__device__ inline ushort_t f2bf(float f) {
    __hip_bfloat16 h = __float2bfloat16(f);
    return *reinterpret_cast<ushort_t*>(&h);
}

__device__ inline u16x8 pack8(float4 a, float4 b) {
    u16x8 o;
    o[0] = f2bf(a.x); o[1] = f2bf(a.y); o[2] = f2bf(a.z); o[3] = f2bf(a.w);
    o[4] = f2bf(b.x); o[5] = f2bf(b.y); o[6] = f2bf(b.z); o[7] = f2bf(b.w);
    return o;
}

// ---------------------------------------------------------------------------
__global__ __launch_bounds__(256) void zero_kernel(float* __restrict__ p, int n) {
    int i = blockIdx.x * 256 + threadIdx.x;
    if (i < n) p[i] = 0.0f;
}

// ---------------------------------------------------------------------------
// Pipelined MFMA projection: out[m][c] = sum_k A[m][k]*W[c][k], fp32 in, bf16 out.
// 128x128 tile, BK=32 (8 iters), 1-deep VGPR prefetch (verified 120us / 92 VGPR;
// 2-deep + launch_bounds(,4) spills -> 2x regression, round-2 post-mortem).
// Double-buffered LDS, ONE raw s_barrier per iter. Fused per-column sum-of-squares.
__global__ __launch_bounds__(256) void proj_mfma(
    const float* __restrict__ x1, const float* __restrict__ x2,
    const float* __restrict__ Wq, const float* __restrict__ Wk,
    const float* __restrict__ Wv,
    ushort_t* __restrict__ qp, ushort_t* __restrict__ kp, ushort_t* __restrict__ vp,
    float* __restrict__ ssq, float* __restrict__ ssk)
{
    const float* A; const float* W; ushort_t* outp; float* ss;
    if (blockIdx.z == 0)      { A = x1; W = Wq; outp = qp; ss = ssq; }
    else if (blockIdx.z == 1) { A = x2; W = Wk; outp = kp; ss = ssk; }
    else                      { A = x2; W = Wv; outp = vp; ss = nullptr; }

    // LDS 16B-slot layout per buffer: slot = kg*128 + row (kg = k/8 within BK=32)
    __shared__ ushort_t Asl[2][4096];   // 2 x 8 KB
    __shared__ ushort_t Bsl[2][4096];
    __shared__ float colss[128];

    const int t = threadIdx.x;
    const int lane = t & 63, w = t >> 6;
    const int l16 = lane & 15, quad = lane >> 4;
    const int m0 = blockIdx.x * 128, c0 = blockIdx.y * 128;
    const int wm = (w >> 1) * 64, wn = (w & 1) * 64;

    const int srow = t >> 1;   // 0..127
    const int skh  = t & 1;    // k-half: floats [skh*16, skh*16+16)

    const float* Ap = A + (size_t)(m0 + srow) * CDIM + skh * 16;
    const float* Wp = W + (size_t)(c0 + srow) * CDIM + skh * 16;

    float4 ga[4], gb[4];
#pragma unroll
    for (int i = 0; i < 4; ++i) {
        ga[i] = *(const float4*)(Ap + i * 4);
        gb[i] = *(const float4*)(Wp + i * 4);
    }

    f32x4 acc[4][4] = {};

#pragma unroll 2
    for (int it = 0; it < 8; ++it) {
        ushort_t* As = Asl[it & 1];
        ushort_t* Bs = Bsl[it & 1];
        *(u16x8*)&As[(skh * 2 + 0) * 1024 + srow * 8] = pack8(ga[0], ga[1]);
        *(u16x8*)&As[(skh * 2 + 1) * 1024 + srow * 8] = pack8(ga[2], ga[3]);
        *(u16x8*)&Bs[(skh * 2 + 0) * 1024 + srow * 8] = pack8(gb[0], gb[1]);
        *(u16x8*)&Bs[(skh * 2 + 1) * 1024 + srow * 8] = pack8(gb[2], gb[3]);
        if (it < 7) {
            int ko = (it + 1) * 32;
#pragma unroll
            for (int i = 0; i < 4; ++i) {
                ga[i] = *(const float4*)(Ap + ko + i * 4);
                gb[i] = *(const float4*)(Wp + ko + i * 4);
            }
        }
        asm volatile("s_waitcnt lgkmcnt(0)" ::: "memory");
        __builtin_amdgcn_s_barrier();
        bf16x8 aF[4], bF[4];
#pragma unroll
        for (int i = 0; i < 4; ++i)
            aF[i] = *(const bf16x8*)&As[quad * 1024 + (wm + i * 16 + l16) * 8];
#pragma unroll
        for (int j = 0; j < 4; ++j)
            bF[j] = *(const bf16x8*)&Bs[quad * 1024 + (wn + j * 16 + l16) * 8];
#pragma unroll
        for (int i = 0; i < 4; ++i)
#pragma unroll
            for (int j = 0; j < 4; ++j)
                acc[i][j] = __builtin_amdgcn_mfma_f32_16x16x32_bf16(aF[i], bF[j], acc[i][j], 0, 0, 0);
    }

    // epilogue: C/D layout col=lane&15, row=quad*4+reg
#pragma unroll
    for (int i = 0; i < 4; ++i) {
#pragma unroll
        for (int j = 0; j < 4; ++j) {
            int col = c0 + wn + j * 16 + l16;
#pragma unroll
            for (int reg = 0; reg < 4; ++reg) {
                int row = m0 + wm + i * 16 + quad * 4 + reg;
                outp[(size_t)row * CDIM + col] = f2bf(acc[i][j][reg]);
            }
        }
    }

    if (ss) {
        __syncthreads();
        if (t < 128) colss[t] = 0.0f;
        __syncthreads();
#pragma unroll
        for (int j = 0; j < 4; ++j) {
            float s = 0.0f;
#pragma unroll
            for (int i = 0; i < 4; ++i)
#pragma unroll
                for (int reg = 0; reg < 4; ++reg)
                    s += acc[i][j][reg] * acc[i][j][reg];
            atomicAdd(&colss[wn + j * 16 + l16], s);
        }
        __syncthreads();
        if (t < 128) {
            int b = m0 >> 13;   // 128-row tile never crosses a batch
            atomicAdd(&ss[b * CDIM + c0 + t], colss[t]);
        }
    }
}

// ---------------------------------------------------------------------------
// MFMA Gram: Gpart[slab][b][h][d][e] = sum_{n in slab} qp[b][n][h*64+d]*kp[b][n][h*64+e]
// grid (16 slabs, H, B). Stage [64 c][128 n] transposed in LDS (stride 144).
// 1-deep chunk prefetch. OUTPUT: plain coalesced stores to per-slab partials
// (replaces 2.1M contended global atomicAdds; reduction folded into softmax_weff).
__global__ __launch_bounds__(256) void gram_mfma(
    const ushort_t* __restrict__ qp, const ushort_t* __restrict__ kp,
    float* __restrict__ Gpart)
{
    constexpr int NS = 144;  // padded n-stride (16B-aligned, b128-conflict-free)
    __shared__ ushort_t qs[64 * NS];   // 18 KB
    __shared__ ushort_t ks2[64 * NS];  // 18 KB
    __shared__ float gsum[4096];       // 16 KB

    const int t = threadIdx.x;
    const int lane = t & 63, w = t >> 6;
    const int l16 = lane & 15, quad = lane >> 4;
    const int slab = blockIdx.x, h = blockIdx.y, b = blockIdx.z;
    const size_t base = (size_t)b * NTOK * CDIM + h * DHEAD;

    const int cg  = t >> 5;   // 0..7 -> channels cg*8..+7
    const int ng4 = t & 31;   // 0..31 -> tokens ng4*4..+3

    for (int i = t; i < 4096; i += 256) gsum[i] = 0.0f;

    f32x4 acc[4][4] = {};

    u16x8 qv[2][4], kv[2][4];
#pragma unroll
    for (int i = 0; i < 4; ++i) {
        size_t g = base + (size_t)(slab * 512 + ng4 * 4 + i) * CDIM + cg * 8;
        qv[0][i] = *(const u16x8*)&qp[g];
        kv[0][i] = *(const u16x8*)&kp[g];
    }

#pragma unroll
    for (int cch = 0; cch < 4; ++cch) {
        const int p = cch & 1;
        __syncthreads();   // previous chunk's LDS reads complete
#pragma unroll
        for (int j = 0; j < 8; ++j) {
            u16x4 wq, wk;
            wq[0] = qv[p][0][j]; wq[1] = qv[p][1][j]; wq[2] = qv[p][2][j]; wq[3] = qv[p][3][j];
            wk[0] = kv[p][0][j]; wk[1] = kv[p][1][j]; wk[2] = kv[p][2][j]; wk[3] = kv[p][3][j];
            *(u16x4*)&qs[(cg * 8 + j) * NS + ng4 * 4] = wq;
            *(u16x4*)&ks2[(cg * 8 + j) * NS + ng4 * 4] = wk;
        }
        if (cch < 3) {
#pragma unroll
            for (int i = 0; i < 4; ++i) {
                size_t g = base + (size_t)(slab * 512 + (cch + 1) * 128 + ng4 * 4 + i) * CDIM + cg * 8;
                qv[p ^ 1][i] = *(const u16x8*)&qp[g];
                kv[p ^ 1][i] = *(const u16x8*)&kp[g];
            }
        }
        __syncthreads();
        // wave w computes tokens [w*32, w*32+32): A[m=d][k=n], B[k=n][col=e]
        bf16x8 aF[4], bF[4];
#pragma unroll
        for (int i = 0; i < 4; ++i)
            aF[i] = *(const bf16x8*)&qs[(i * 16 + l16) * NS + w * 32 + quad * 8];
#pragma unroll
        for (int j = 0; j < 4; ++j)
            bF[j] = *(const bf16x8*)&ks2[(j * 16 + l16) * NS + w * 32 + quad * 8];
#pragma unroll
        for (int i = 0; i < 4; ++i)
#pragma unroll
            for (int j = 0; j < 4; ++j)
                acc[i][j] = __builtin_amdgcn_mfma_f32_16x16x32_bf16(aF[i], bF[j], acc[i][j], 0, 0, 0);
    }

    __syncthreads();
#pragma unroll
    for (int i = 0; i < 4; ++i)
#pragma unroll
        for (int j = 0; j < 4; ++j)
#pragma unroll
            for (int reg = 0; reg < 4; ++reg)
                atomicAdd(&gsum[(i * 16 + quad * 4 + reg) * 64 + j * 16 + l16], acc[i][j][reg]);
    __syncthreads();

    float* Gp = Gpart + ((size_t)slab * BDIM * HEADS + b * HEADS + h) * 4096;
    for (int i = t; i < 4096; i += 256) Gp[i] = gsum[i];
}

// ---------------------------------------------------------------------------
// K3 (fused): 16-slab reduction + normalize + temperature + row softmax (in LDS)
// then W_eff[b][c][h*64+e] = sum_d Wo[c][h*64+d] * attn[d][e], bf16 out.
// Softmax: 4 lanes per row (16 cols each), shfl_xor combine within wave.
__global__ __launch_bounds__(256) void softmax_weff(
    const float* __restrict__ Gpart, const float* __restrict__ ssq,
    const float* __restrict__ ssk, const float* __restrict__ temp,
    const float* __restrict__ Wo, ushort_t* __restrict__ Weffb)
{
    const int h = blockIdx.x, b = blockIdx.y;
    const int t = threadIdx.x;
    __shared__ float at[64][65];
    __shared__ float nk[64];

    if (t < 64) nk[t] = fmaxf(sqrtf(ssk[b * CDIM + h * DHEAD + t]), 1e-12f);
    __syncthreads();

    {
        const int row = t >> 2, part = t & 3;
        const size_t sstride = (size_t)BDIM * HEADS * 4096;
        const float* Gbase = Gpart + (size_t)(b * HEADS + h) * 4096 + row * 64 + part * 16;
        const float tmp = temp[h];
        const float nq = fmaxf(sqrtf(ssq[b * CDIM + h * DHEAD + row]), 1e-12f);

        float sum[16];
#pragma unroll
        for (int j = 0; j < 16; ++j) sum[j] = 0.0f;
#pragma unroll
        for (int s = 0; s < NSLAB; ++s) {
            const float4* gp = (const float4*)(Gbase + (size_t)s * sstride);
#pragma unroll
            for (int q4 = 0; q4 < 4; ++q4) {
                float4 v = gp[q4];
                sum[q4 * 4 + 0] += v.x; sum[q4 * 4 + 1] += v.y;
                sum[q4 * 4 + 2] += v.z; sum[q4 * 4 + 3] += v.w;
            }
        }

        float vals[16];
        float mx = -1e30f;
#pragma unroll
        for (int j = 0; j < 16; ++j) {
            int e = part * 16 + j;
            float v = sum[j] / (nq * nk[e]) * tmp;
            vals[j] = v;
            mx = fmaxf(mx, v);
        }
        mx = fmaxf(mx, __shfl_xor(mx, 1));
        mx = fmaxf(mx, __shfl_xor(mx, 2));
        float s = 0.0f;
#pragma unroll
        for (int j = 0; j < 16; ++j) {
            float ev = __expf(vals[j] - mx);
            vals[j] = ev;
            s += ev;
        }
        s += __shfl_xor(s, 1);
        s += __shfl_xor(s, 2);
        float inv = 1.0f / s;
#pragma unroll
        for (int j = 0; j < 16; ++j)
            at[row][part * 16 + j] = vals[j] * inv;
    }
    __syncthreads();

    const int c = t;
    float wo[64];
#pragma unroll
    for (int d2 = 0; d2 < 64; ++d2) wo[d2] = Wo[(size_t)c * CDIM + h * DHEAD + d2];

    ushort_t* Wb = Weffb + (size_t)b * CDIM * CDIM + (size_t)c * CDIM + h * DHEAD;
#pragma unroll 4
    for (int e = 0; e < 64; ++e) {
        float s = 0.0f;
#pragma unroll
        for (int d2 = 0; d2 < 64; ++d2) s += wo[d2] * at[d2][e];
        Wb[e] = f2bf(s);
    }
}

// ---------------------------------------------------------------------------
// Pipelined MFMA output GEMM: out[m][c] = bo[c] + sum_k vp[m][k]*Weffb[b][c][k]
// Same single-barrier dbuf skeleton as proj_mfma, bf16 inputs (no cvt).
__global__ __launch_bounds__(256) void out_mfma(
    const ushort_t* __restrict__ vp, const ushort_t* __restrict__ Weffb,
    const float* __restrict__ bo, float* __restrict__ out)
{
    __shared__ ushort_t Asl[2][4096];
    __shared__ ushort_t Bsl[2][4096];

    const int t = threadIdx.x;
    const int lane = t & 63, w = t >> 6;
    const int l16 = lane & 15, quad = lane >> 4;
    const int m0 = blockIdx.x * 128, c0 = blockIdx.y * 128;
    const int wm = (w >> 1) * 64, wn = (w & 1) * 64;

    const int srow = t >> 1;
    const int skh  = t & 1;

    const ushort_t* Ap = vp + (size_t)(m0 + srow) * CDIM + skh * 16;
    const ushort_t* Bp = Weffb + (size_t)(m0 >> 13) * CDIM * CDIM
                       + (size_t)(c0 + srow) * CDIM + skh * 16;

    u16x8 ga0 = *(const u16x8*)Ap,       ga1 = *(const u16x8*)(Ap + 8);
    u16x8 gb0 = *(const u16x8*)Bp,       gb1 = *(const u16x8*)(Bp + 8);

    f32x4 acc[4][4] = {};

#pragma unroll 2
    for (int it = 0; it < 8; ++it) {
        ushort_t* As = Asl[it & 1];
        ushort_t* Bs = Bsl[it & 1];
        *(u16x8*)&As[(skh * 2 + 0) * 1024 + srow * 8] = ga0;
        *(u16x8*)&As[(skh * 2 + 1) * 1024 + srow * 8] = ga1;
        *(u16x8*)&Bs[(skh * 2 + 0) * 1024 + srow * 8] = gb0;
        *(u16x8*)&Bs[(skh * 2 + 1) * 1024 + srow * 8] = gb1;
        if (it < 7) {
            int ko = (it + 1) * 32;
            ga0 = *(const u16x8*)(Ap + ko);
            ga1 = *(const u16x8*)(Ap + ko + 8);
            gb0 = *(const u16x8*)(Bp + ko);
            gb1 = *(const u16x8*)(Bp + ko + 8);
        }
        asm volatile("s_waitcnt lgkmcnt(0)" ::: "memory");
        __builtin_amdgcn_s_barrier();
        bf16x8 aF[4], bF[4];
#pragma unroll
        for (int i = 0; i < 4; ++i)
            aF[i] = *(const bf16x8*)&As[quad * 1024 + (wm + i * 16 + l16) * 8];
#pragma unroll
        for (int j = 0; j < 4; ++j)
            bF[j] = *(const bf16x8*)&Bs[quad * 1024 + (wn + j * 16 + l16) * 8];
#pragma unroll
        for (int i = 0; i < 4; ++i)
#pragma unroll
            for (int j = 0; j < 4; ++j)
                acc[i][j] = __builtin_amdgcn_mfma_f32_16x16x32_bf16(aF[i], bF[j], acc[i][j], 0, 0, 0);
    }

#pragma unroll
    for (int i = 0; i < 4; ++i) {
#pragma unroll
        for (int j = 0; j < 4; ++j) {
            int col = c0 + wn + j * 16 + l16;
            float bias = bo[col];
#pragma unroll
            for (int reg = 0; reg < 4; ++reg) {
                int row = m0 + wm + i * 16 + quad * 4 + reg;
                out[(size_t)row * CDIM + col] = acc[i][j][reg] + bias;
            }
        }
    }
}

// ---------------------------------------------------------------------------
extern "C" void kernel_launch(void* const* d_in, const int* in_sizes, int n_in,
                              void* d_out, int out_size, void* d_ws, size_t ws_size,
                              hipStream_t stream) {
    const float* x1   = (const float*)d_in[0];
    const float* x2   = (const float*)d_in[1];
    const float* Wq   = (const float*)d_in[2];
    const float* Wk   = (const float*)d_in[3];
    const float* Wv   = (const float*)d_in[4];
    const float* Wo   = (const float*)d_in[5];
    const float* bo   = (const float*)d_in[6];
    const float* temp = (const float*)d_in[7];
    float* out = (float*)d_out;

    char* ws = (char*)d_ws;
    const size_t SZP = (size_t)MROWS * CDIM * sizeof(ushort_t);   // 32 MB
    ushort_t* qp   = (ushort_t*)(ws);
    ushort_t* kp   = (ushort_t*)(ws + SZP);
    ushort_t* vp   = (ushort_t*)(ws + 2 * SZP);
    float*    ssq  = (float*)(ws + 3 * SZP);                 // 8 KB
    float*    ssk  = (float*)(ws + 3 * SZP + 8192);          // 8 KB
    float*    Gpart= (float*)(ws + 3 * SZP + 16384);         // 16 slabs x 32 x 4096 f32 = 8 MB
    ushort_t* Weffb= (ushort_t*)(ws + 3 * SZP + 16384 + (size_t)NSLAB * BDIM * HEADS * 4096 * 4);  // 1 MB

    // zero ssq+ssk (contiguous, 4096 floats); Gpart is fully overwritten
    zero_kernel<<<dim3((4096 + 255) / 256), dim3(256), 0, stream>>>(ssq, 4096);

    proj_mfma<<<dim3(MROWS / 128, CDIM / 128, 3), dim3(256), 0, stream>>>(
        x1, x2, Wq, Wk, Wv, qp, kp, vp, ssq, ssk);

    gram_mfma<<<dim3(NSLAB, HEADS, BDIM), dim3(256), 0, stream>>>(qp, kp, Gpart);

    softmax_weff<<<dim3(HEADS, BDIM), dim3(256), 0, stream>>>(Gpart, ssq, ssk, temp, Wo, Weffb);

    out_mfma<<<dim3(MROWS / 128, CDIM / 128), dim3(256), 0, stream>>>(vp, Weffb, bo, out);
}